// Round 2
// baseline (1126.862 us; speedup 1.0000x reference)
//
#include <hip/hip_runtime.h>
#include <stdint.h>
#include <stddef.h>

#define HIDDEN 2048
#define INTER  5632
#define TOKENS 4096   // B*S = 2*2048
#define BK     64     // K-tile for both GEMMs (i8: 64B rows, f16: 128B rows)

typedef __attribute__((ext_vector_type(8))) _Float16 f16x8;
typedef __attribute__((ext_vector_type(4))) _Float16 f16x4;
typedef __attribute__((ext_vector_type(4))) float    f32x4;
typedef __attribute__((ext_vector_type(4))) int      i32x4;

// 128B-row LDS swizzle (8 x 16B segs), period-8 row rotation: global segment q
// of row r lives at slot r*8 + ((q+r)&7).  ds_read_b128 conflict unit is an
// 8-lane phase (8 x 16B = all 32 banks): for fixed q, 8 consecutive rows map
// to 8 DISTINCT bank-quads -> conflict-free (verified 0 conflicts, R0).
__device__ __forceinline__ int swz8(int row, int q) { return row * 8 + ((q + row) & 7); }

// 64B-row PAIRED layout: two matrix rows share one 128B LDS row.
// slot(m,q) = (m>>1)*8 + (m&1)*4 + ((q + (m>>1)) & 3).
// Read phase check (8 lanes, fixed q, rows m..m+7): slots mod 8 =
// {q,q+4,(q+1),(q+1)+4,(q+2),(q+2)+4,(q+3),(q+3)+4} -> all 8 distinct ->
// conflict-free.  Staging inverse is the identity: f = slot(m(f),q(f)) with
// m = 2*(f>>3)+((f>>2)&1), q = ((f&3)-(f>>3))&3, so global_load_lds can write
// linearly at f*16 (wave-uniform base + lane*16 requirement holds).
__device__ __forceinline__ int slotGU(int m, int q) {
    return (m >> 1) * 8 + (m & 1) * 4 + ((q + (m >> 1)) & 3);
}

#define GLDS16(g, l) __builtin_amdgcn_global_load_lds( \
    (__attribute__((address_space(1))) void*)(g), \
    (__attribute__((address_space(3))) void*)(l), 16, 0, 0)

// ---------------------------------------------------------------------------
// fused prepass: blocks [0,TOKENS) quantize x per-token to i8;
// blocks [TOKENS, TOKENS+2048) grid-stride convert weights
// ---------------------------------------------------------------------------
__global__ __launch_bounds__(256)
void prepass(const float* __restrict__ x,
             const float4* __restrict__ gw, const float4* __restrict__ uw,
             const float4* __restrict__ dw,
             int8_t* __restrict__ xq, float* __restrict__ xs,
             int* __restrict__ go, int* __restrict__ uo,
             f16x4* __restrict__ dno) {
    const int tid = threadIdx.x;
    if (blockIdx.x < TOKENS) {
        const int t = blockIdx.x;
        const float4* row = (const float4*)(x + (size_t)t * HIDDEN);
        float4 v0 = row[tid * 2];
        float4 v1 = row[tid * 2 + 1];
        float m = fmaxf(fmaxf(fabsf(v0.x), fabsf(v0.y)), fmaxf(fabsf(v0.z), fabsf(v0.w)));
        m = fmaxf(m, fmaxf(fmaxf(fabsf(v1.x), fabsf(v1.y)), fmaxf(fabsf(v1.z), fabsf(v1.w))));
        #pragma unroll
        for (int off = 32; off; off >>= 1)
            m = fmaxf(m, __shfl_xor(m, off, 64));
        __shared__ float wmax[4];
        if ((tid & 63) == 0) wmax[tid >> 6] = m;
        __syncthreads();
        m = fmaxf(fmaxf(wmax[0], wmax[1]), fmaxf(wmax[2], wmax[3]));
        m = fmaxf(m, 1e-20f);
        if (tid == 0) xs[t] = m * (1.0f / 127.0f);
        const float inv = 127.0f / m;
        float vals[8] = {v0.x, v0.y, v0.z, v0.w, v1.x, v1.y, v1.z, v1.w};
        int b[8];
        #pragma unroll
        for (int i = 0; i < 8; ++i) b[i] = (int)rintf(vals[i] * inv);
        int lo = (b[0] & 255) | ((b[1] & 255) << 8) | ((b[2] & 255) << 16) | (b[3] << 24);
        int hi = (b[4] & 255) | ((b[5] & 255) << 8) | ((b[6] & 255) << 16) | (b[7] << 24);
        ((int2*)(xq + (size_t)t * HIDDEN))[tid] = make_int2(lo, hi);
        return;
    }
    const int NW4 = INTER * HIDDEN / 4;
    int i = (blockIdx.x - TOKENS) * blockDim.x + tid;
    const int stride = 2048 * blockDim.x;
    for (; i < 3 * NW4; i += stride) {
        if (i < 2 * NW4) {
            const bool is_g = i < NW4;
            const int j = is_g ? i : i - NW4;
            float4 f = is_g ? gw[j] : uw[j];
            int p = ((int)(signed char)(int)f.x & 255)
                  | (((int)(signed char)(int)f.y & 255) << 8)
                  | (((int)(signed char)(int)f.z & 255) << 16)
                  | (((int)(signed char)(int)f.w) << 24);
            if (is_g) go[j] = p; else uo[j] = p;
        } else {
            const int j = i - 2 * NW4;
            float4 f = dw[j];
            f16x4 o;
            o.x = (_Float16)f.x; o.y = (_Float16)f.y;
            o.z = (_Float16)f.z; o.w = (_Float16)f.w;
            dno[j] = o;
        }
    }
}

// ---------------------------------------------------------------------------
// GEMM1 fused (i8): H = silu(G*xs*gs) * (U*xs*us)  (fp16 out)
// 128x128 tile, BK=64 (32 K-iters), LDS 24KB single-buffer -> 4 blocks/CU
// (16 waves, was 2 blocks/6 waves at BK=128/48KB).  Same 2-barrier
// compiler-scheduled structure as the 105us R0 kernel; the extra barrier
// groups hide each other's staging drains (m114 TLP overlap).
// Paired-row LDS layout keeps ds_read_b128 conflict-free at 64B rows.
// ---------------------------------------------------------------------------
__global__ __launch_bounds__(256, 4)
void gemm_gateup(const int8_t* __restrict__ Xq,
                 const int8_t* __restrict__ Wg,
                 const int8_t* __restrict__ Wu,
                 const float* __restrict__ xs,
                 const float* __restrict__ gs,
                 const float* __restrict__ us,
                 _Float16* __restrict__ Hm) {
    __shared__ int8_t As [128 * BK];   // 8KB
    __shared__ int8_t Bgs[128 * BK];   // 8KB
    __shared__ int8_t Bus[128 * BK];   // 8KB

    const int pid   = blockIdx.x;          // 0..1407
    const int local = pid % (16 * 44);
    const int bm    = ((pid / (16 * 44)) * 16 + (local & 15)) * 128;
    const int bn    = (local >> 4) * 128;

    const int tid  = threadIdx.x;
    const int lane = tid & 63;
    const int wave = tid >> 6;
    const int wm   = (wave >> 1) * 64;
    const int wn   = (wave & 1) * 64;
    const int l15  = lane & 15;
    const int lq   = lane >> 4;

    // staging: 512 16B-slots per matrix per tile; slot f (paired-row layout):
    // row = 2*(f>>3) + ((f>>2)&1), seg = ((f&3) - (f>>3)) & 3.
    int rowS[2], segS[2];
    #pragma unroll
    for (int j = 0; j < 2; ++j) {
        const int f = tid + 256 * j;
        rowS[j] = 2 * (f >> 3) + ((f >> 2) & 1);
        segS[j] = (((f & 3) - (f >> 3)) & 3) * 16;
    }

    i32x4 accg[4][4] = {};
    i32x4 accu[4][4] = {};

    for (int k0 = 0; k0 < HIDDEN; k0 += BK) {
        #pragma unroll
        for (int j = 0; j < 2; ++j) {
            const int f = tid + 256 * j;
            const size_t off = (size_t)rowS[j] * HIDDEN + k0 + segS[j];
            GLDS16(Xq + (size_t)bm * HIDDEN + off, &As [f * 16]);
            GLDS16(Wg + (size_t)bn * HIDDEN + off, &Bgs[f * 16]);
            GLDS16(Wu + (size_t)bn * HIDDEN + off, &Bus[f * 16]);
        }
        __syncthreads();

        i32x4 a[4];
        #pragma unroll
        for (int im = 0; im < 4; ++im)
            a[im] = *(const i32x4*)&As[slotGU(wm + im * 16 + l15, lq) * 16];
        #pragma unroll
        for (int jn = 0; jn < 4; ++jn) {
            i32x4 bg = *(const i32x4*)&Bgs[slotGU(wn + jn * 16 + l15, lq) * 16];
            i32x4 bu = *(const i32x4*)&Bus[slotGU(wn + jn * 16 + l15, lq) * 16];
            #pragma unroll
            for (int im = 0; im < 4; ++im) {
                accg[im][jn] = __builtin_amdgcn_mfma_i32_16x16x64_i8(a[im], bg, accg[im][jn], 0, 0, 0);
                accu[im][jn] = __builtin_amdgcn_mfma_i32_16x16x64_i8(a[im], bu, accu[im][jn], 0, 0, 0);
            }
        }
        __syncthreads();
    }

    #pragma unroll
    for (int jn = 0; jn < 4; ++jn) {
        const int col = bn + wn + jn * 16 + l15;
        const float sg = gs[col];
        const float su = us[col];
        #pragma unroll
        for (int im = 0; im < 4; ++im) {
            const int rbase = bm + wm + im * 16 + lq * 4;
            #pragma unroll
            for (int r = 0; r < 4; ++r) {
                const int row = rbase + r;
                const float st = xs[row];
                float g = (float)accg[im][jn][r] * st * sg;
                float u = (float)accu[im][jn][r] * st * su;
                float h = (g / (1.0f + __expf(-g))) * u;
                Hm[(size_t)row * INTER + col] = (_Float16)h;
            }
        }
    }
}

// ---------------------------------------------------------------------------
// GEMM2 (fp16): out = (H @ Wd^T) * down_s  (fp32 out)
// 128x64 tile, 128 threads (2 waves, each 64x64), BK=64 (88 K-iters),
// LDS 24KB -> 6 blocks/CU (12 waves; was grid-limited to 2 blocks/8 waves at
// 128x128/512 blocks).  Same 2-barrier structure, swz8 layout (128B f16 rows,
// conflict-free).  Grid 1024: bands of 16 m-tiles x 32 n-tiles; consecutive
// pids share one 0.7MB Wd panel (L2-friendly).
// ---------------------------------------------------------------------------
__global__ __launch_bounds__(128, 3)
void gemm_down(const _Float16* __restrict__ Hm,
               const _Float16* __restrict__ Wd,
               const float* __restrict__ dsc,
               float* __restrict__ out) {
    __shared__ _Float16 As[128 * BK];   // 16KB
    __shared__ _Float16 Bs[ 64 * BK];   // 8KB

    const int pid = blockIdx.x;            // 0..1023
    const int loc = pid & 511;
    const int bm  = ((pid >> 9) * 16 + (loc & 15)) * 128;
    const int bn  = (loc >> 4) * 64;

    const int tid  = threadIdx.x;          // 0..127
    const int lane = tid & 63;
    const int wave = tid >> 6;             // 0..1
    const int wm   = wave * 64;
    const int l15  = lane & 15;
    const int lq   = lane >> 4;

    // staging (swz8, 128B rows): A = 1024 slots (8 rounds of 128 thr),
    // B = 512 slots (4 rounds).
    int rS[8], sS[8];
    #pragma unroll
    for (int j = 0; j < 8; ++j) {
        const int f = tid + 128 * j;
        rS[j] = f >> 3;
        sS[j] = (((f & 7) - (f >> 3)) & 7) * 8;   // f16 elements
    }

    f32x4 acc[4][4] = {};

    for (int k0 = 0; k0 < INTER; k0 += BK) {
        #pragma unroll
        for (int j = 0; j < 8; ++j) {
            const int f = tid + 128 * j;
            GLDS16(Hm + (size_t)(bm + rS[j]) * INTER + k0 + sS[j], &As[f * 8]);
        }
        #pragma unroll
        for (int j = 0; j < 4; ++j) {
            const int f = tid + 128 * j;
            GLDS16(Wd + (size_t)(bn + rS[j]) * INTER + k0 + sS[j], &Bs[f * 8]);
        }
        __syncthreads();

        #pragma unroll
        for (int ks = 0; ks < 2; ++ks) {
            const int q = ks * 4 + lq;
            f16x8 a[4];
            #pragma unroll
            for (int im = 0; im < 4; ++im)
                a[im] = *(const f16x8*)&As[swz8(wm + im * 16 + l15, q) * 8];
            #pragma unroll
            for (int jn = 0; jn < 4; ++jn) {
                f16x8 b = *(const f16x8*)&Bs[swz8(jn * 16 + l15, q) * 8];
                #pragma unroll
                for (int im = 0; im < 4; ++im)
                    acc[im][jn] = __builtin_amdgcn_mfma_f32_16x16x32_f16(a[im], b, acc[im][jn], 0, 0, 0);
            }
        }
        __syncthreads();
    }

    #pragma unroll
    for (int jn = 0; jn < 4; ++jn) {
        const int col = bn + jn * 16 + l15;
        const float sd = dsc[col];
        #pragma unroll
        for (int im = 0; im < 4; ++im) {
            const int rbase = bm + wm + im * 16 + lq * 4;
            #pragma unroll
            for (int r = 0; r < 4; ++r)
                out[(size_t)(rbase + r) * HIDDEN + col] = acc[im][jn][r] * sd;
        }
    }
}

// ---------------------------------------------------------------------------
// launch
// ---------------------------------------------------------------------------
extern "C" void kernel_launch(void* const* d_in, const int* in_sizes, int n_in,
                              void* d_out, int out_size, void* d_ws, size_t ws_size,
                              hipStream_t stream) {
    const float* x   = (const float*)d_in[0];
    const float* gw  = (const float*)d_in[1];
    const float* uw  = (const float*)d_in[2];
    const float* dw  = (const float*)d_in[3];
    const float* gsc = (const float*)d_in[4];
    const float* usc = (const float*)d_in[5];
    const float* dsc = (const float*)d_in[6];
    float* out = (float*)d_out;

    // workspace layout:
    //   Xq  i8  @          0 :  8,388,608
    //   Wg8 i8  @  8,388,608 : 11,534,336
    //   Wu8 i8  @ 19,922,944 : 11,534,336
    //   Wdh f16 @ 31,457,280 : 23,068,672
    //   Hm  f16 @ 54,525,952 : 46,137,344
    //   xs  f32 @100,663,296 :     16,384
    char* ws = (char*)d_ws;
    int8_t*   Xq  = (int8_t*)(ws);
    int8_t*   Wg8 = (int8_t*)(ws + 8388608ull);
    int8_t*   Wu8 = (int8_t*)(ws + 19922944ull);
    _Float16* Wdh = (_Float16*)(ws + 31457280ull);
    _Float16* Hm  = (_Float16*)(ws + 54525952ull);
    float*    xs  = (float*)(ws + 100663296ull);

    prepass<<<TOKENS + 2048, 256, 0, stream>>>(
        x, (const float4*)gw, (const float4*)uw, (const float4*)dw,
        Xq, xs, (int*)Wg8, (int*)Wu8, (f16x4*)Wdh);

    gemm_gateup<<<(INTER / 128) * (TOKENS / 128), 256, 0, stream>>>(
        Xq, Wg8, Wu8, xs, gsc, usc, Hm);
    gemm_down<<<(HIDDEN / 128) * (TOKENS / 64), 128, 0, stream>>>(
        Hm, Wdh, dsc, out);
}

// Round 3
// 412.227 us; speedup vs baseline: 2.7336x; 2.7336x over previous
//
#include <hip/hip_runtime.h>
#include <stdint.h>
#include <stddef.h>

#define HIDDEN 2048
#define INTER  5632
#define TOKENS 4096   // B*S = 2*2048
#define BK     64     // K-tile both GEMMs (i8: 64B rows, f16: 128B rows)
#define NT_GU  (HIDDEN / BK)   // 32
#define NT_DN  (INTER / BK)    // 88

typedef __attribute__((ext_vector_type(8))) _Float16 f16x8;
typedef __attribute__((ext_vector_type(4))) _Float16 f16x4;
typedef __attribute__((ext_vector_type(4))) float    f32x4;
typedef __attribute__((ext_vector_type(4))) int      i32x4;

// 128B-row LDS swizzle (8 x 16B segs), period-8 row rotation: global segment q
// of row r lives at slot r*8 + ((q+r)&7).  ds_read_b128 conflict unit is an
// 8-lane phase (8 x 16B = all 32 banks): fixed q -> 8 consecutive rows hit 8
// DISTINCT bank-quads -> conflict-free (verified: 0 conflicts, R0).
__device__ __forceinline__ int swz8(int row, int q) { return row * 8 + ((q + row) & 7); }

// 64B-row PAIRED layout: two matrix rows share one 128B LDS row.
// slot(m,q) = (m>>1)*8 + (m&1)*4 + ((q + (m>>1)) & 3).
// HW-verified R2: SQ_LDS_BANK_CONFLICT = 0 and results correct.
__device__ __forceinline__ int slotGU(int m, int q) {
    return (m >> 1) * 8 + (m & 1) * 4 + ((q + (m >> 1)) & 3);
}

#define GLDS16(g, l) __builtin_amdgcn_global_load_lds( \
    (__attribute__((address_space(1))) void*)(g), \
    (__attribute__((address_space(3))) void*)(l), 16, 0, 0)

// ---------------------------------------------------------------------------
// fused prepass: blocks [0,TOKENS) quantize x per-token to i8;
// blocks [TOKENS, TOKENS+2048) grid-stride convert weights
// ---------------------------------------------------------------------------
__global__ __launch_bounds__(256)
void prepass(const float* __restrict__ x,
             const float4* __restrict__ gw, const float4* __restrict__ uw,
             const float4* __restrict__ dw,
             int8_t* __restrict__ xq, float* __restrict__ xs,
             int* __restrict__ go, int* __restrict__ uo,
             f16x4* __restrict__ dno) {
    const int tid = threadIdx.x;
    if (blockIdx.x < TOKENS) {
        const int t = blockIdx.x;
        const float4* row = (const float4*)(x + (size_t)t * HIDDEN);
        float4 v0 = row[tid * 2];
        float4 v1 = row[tid * 2 + 1];
        float m = fmaxf(fmaxf(fabsf(v0.x), fabsf(v0.y)), fmaxf(fabsf(v0.z), fabsf(v0.w)));
        m = fmaxf(m, fmaxf(fmaxf(fabsf(v1.x), fabsf(v1.y)), fmaxf(fabsf(v1.z), fabsf(v1.w))));
        #pragma unroll
        for (int off = 32; off; off >>= 1)
            m = fmaxf(m, __shfl_xor(m, off, 64));
        __shared__ float wmax[4];
        if ((tid & 63) == 0) wmax[tid >> 6] = m;
        __syncthreads();
        m = fmaxf(fmaxf(wmax[0], wmax[1]), fmaxf(wmax[2], wmax[3]));
        m = fmaxf(m, 1e-20f);
        if (tid == 0) xs[t] = m * (1.0f / 127.0f);
        const float inv = 127.0f / m;
        float vals[8] = {v0.x, v0.y, v0.z, v0.w, v1.x, v1.y, v1.z, v1.w};
        int b[8];
        #pragma unroll
        for (int i = 0; i < 8; ++i) b[i] = (int)rintf(vals[i] * inv);
        int lo = (b[0] & 255) | ((b[1] & 255) << 8) | ((b[2] & 255) << 16) | (b[3] << 24);
        int hi = (b[4] & 255) | ((b[5] & 255) << 8) | ((b[6] & 255) << 16) | (b[7] << 24);
        ((int2*)(xq + (size_t)t * HIDDEN))[tid] = make_int2(lo, hi);
        return;
    }
    const int NW4 = INTER * HIDDEN / 4;
    int i = (blockIdx.x - TOKENS) * blockDim.x + tid;
    const int stride = 2048 * blockDim.x;
    for (; i < 3 * NW4; i += stride) {
        if (i < 2 * NW4) {
            const bool is_g = i < NW4;
            const int j = is_g ? i : i - NW4;
            float4 f = is_g ? gw[j] : uw[j];
            int p = ((int)(signed char)(int)f.x & 255)
                  | (((int)(signed char)(int)f.y & 255) << 8)
                  | (((int)(signed char)(int)f.z & 255) << 16)
                  | (((int)(signed char)(int)f.w) << 24);
            if (is_g) go[j] = p; else uo[j] = p;
        } else {
            const int j = i - 2 * NW4;
            float4 f = dw[j];
            f16x4 o;
            o.x = (_Float16)f.x; o.y = (_Float16)f.y;
            o.z = (_Float16)f.z; o.w = (_Float16)f.w;
            dno[j] = o;
        }
    }
}

// ---------------------------------------------------------------------------
// GEMM1 fused (i8): H = silu(G*xs*gs) * (U*xs*us)  (fp16 out)
// 128x128 tile, BK=64 (32 K-iters), DOUBLE-buffered LDS 2x24KB = 48KB (same
// total as R0 -> 2 blocks/CU preserved; VGPR budget (256,2) as R0 -> no
// spill).  T3/T4-minimum 2-phase: stage tile t+1 into buf^1, compute tile t,
// ONE __syncthreads per iter -> the vmcnt drain lands AFTER ~650cyc of MFMA
// instead of before compute (R0 stalled pre-MFMA).  Paired-row slotGU layout
// (R2-verified conflict-free).
// ---------------------------------------------------------------------------
__global__ __launch_bounds__(256, 2)
void gemm_gateup(const int8_t* __restrict__ Xq,
                 const int8_t* __restrict__ Wg,
                 const int8_t* __restrict__ Wu,
                 const float* __restrict__ xs,
                 const float* __restrict__ gs,
                 const float* __restrict__ us,
                 _Float16* __restrict__ Hm) {
    __shared__ int8_t As [2][128 * BK];   // 2 x 8KB
    __shared__ int8_t Bgs[2][128 * BK];
    __shared__ int8_t Bus[2][128 * BK];

    const int pid   = blockIdx.x;          // 0..1407
    const int local = pid % (16 * 44);
    const int bm    = ((pid / (16 * 44)) * 16 + (local & 15)) * 128;
    const int bn    = (local >> 4) * 128;

    const int tid  = threadIdx.x;
    const int lane = tid & 63;
    const int wave = tid >> 6;
    const int wm   = (wave >> 1) * 64;
    const int wn   = (wave & 1) * 64;
    const int l15  = lane & 15;
    const int lq   = lane >> 4;

    // staging: 512 16B-slots per matrix per tile; slot f (paired-row layout):
    // row = 2*(f>>3) + ((f>>2)&1), seg = ((f&3) - (f>>3)) & 3.
    int rowS[2], segS[2];
    #pragma unroll
    for (int j = 0; j < 2; ++j) {
        const int f = tid + 256 * j;
        rowS[j] = 2 * (f >> 3) + ((f >> 2) & 1);
        segS[j] = (((f & 3) - (f >> 3)) & 3) * 16;
    }

    const int8_t* gA = Xq + (size_t)bm * HIDDEN;
    const int8_t* gG = Wg + (size_t)bn * HIDDEN;
    const int8_t* gU = Wu + (size_t)bn * HIDDEN;

    i32x4 accg[4][4] = {};
    i32x4 accu[4][4] = {};

    #define STG_GU(b, k0) do { \
        _Pragma("unroll") \
        for (int j = 0; j < 2; ++j) { \
            const int f_ = tid + 256 * j; \
            const size_t off_ = (size_t)rowS[j] * HIDDEN + (size_t)(k0) + segS[j]; \
            GLDS16(gA + off_, &As [b][f_ * 16]); \
            GLDS16(gG + off_, &Bgs[b][f_ * 16]); \
            GLDS16(gU + off_, &Bus[b][f_ * 16]); \
        } \
    } while (0)

    STG_GU(0, 0);
    __syncthreads();

    int cur = 0;
    for (int t = 0; t < NT_GU; ++t) {
        if (t + 1 < NT_GU) STG_GU(cur ^ 1, (t + 1) * BK);

        const int8_t* A_ = As [cur];
        const int8_t* G_ = Bgs[cur];
        const int8_t* U_ = Bus[cur];

        i32x4 a[4];
        #pragma unroll
        for (int im = 0; im < 4; ++im)
            a[im] = *(const i32x4*)&A_[slotGU(wm + im * 16 + l15, lq) * 16];
        #pragma unroll
        for (int jn = 0; jn < 4; ++jn) {
            i32x4 bg = *(const i32x4*)&G_[slotGU(wn + jn * 16 + l15, lq) * 16];
            i32x4 bu = *(const i32x4*)&U_[slotGU(wn + jn * 16 + l15, lq) * 16];
            #pragma unroll
            for (int im = 0; im < 4; ++im) {
                accg[im][jn] = __builtin_amdgcn_mfma_i32_16x16x64_i8(a[im], bg, accg[im][jn], 0, 0, 0);
                accu[im][jn] = __builtin_amdgcn_mfma_i32_16x16x64_i8(a[im], bu, accu[im][jn], 0, 0, 0);
            }
        }
        __syncthreads();   // drains this iter's stage loads AFTER the MFMAs
        cur ^= 1;
    }
    #undef STG_GU

    #pragma unroll
    for (int jn = 0; jn < 4; ++jn) {
        const int col = bn + wn + jn * 16 + l15;
        const float sg = gs[col];
        const float su = us[col];
        #pragma unroll
        for (int im = 0; im < 4; ++im) {
            const int rbase = bm + wm + im * 16 + lq * 4;
            #pragma unroll
            for (int r = 0; r < 4; ++r) {
                const int row = rbase + r;
                const float st = xs[row];
                float g = (float)accg[im][jn][r] * st * sg;
                float u = (float)accu[im][jn][r] * st * su;
                float h = (g / (1.0f + __expf(-g))) * u;
                Hm[(size_t)row * INTER + col] = (_Float16)h;
            }
        }
    }
}

// ---------------------------------------------------------------------------
// GEMM2 (fp16): out = (H @ Wd^T) * down_s  (fp32 out)
// 128x128 tile, BK=64 (88 K-iters), DOUBLE-buffered LDS 2x32KB = 64KB
// (still 2 blocks/CU: VGPR-capped at 2 anyway).  Same 2-phase structure as
// gateup; swz8 layout (128B f16 rows, R0-verified conflict-free).  R0 grid
// (512 blocks, band-swizzled).
// ---------------------------------------------------------------------------
__global__ __launch_bounds__(256, 2)
void gemm_down(const _Float16* __restrict__ Hm,
               const _Float16* __restrict__ Wd,
               const float* __restrict__ dsc,
               float* __restrict__ out) {
    __shared__ _Float16 As[2][128 * BK];   // 2 x 16KB
    __shared__ _Float16 Bs[2][128 * BK];   // 2 x 16KB

    const int pid = blockIdx.x;            // 0..511
    const int loc = pid & 255;
    const int bm  = ((pid >> 8) * 16 + (loc & 15)) * 128;
    const int bn  = (loc >> 4) * 128;

    const int tid  = threadIdx.x;
    const int lane = tid & 63;
    const int wave = tid >> 6;
    const int wm   = (wave >> 1) * 64;
    const int wn   = (wave & 1) * 64;
    const int l15  = lane & 15;
    const int lq   = lane >> 4;

    int rS[4], sS[4];
    #pragma unroll
    for (int j = 0; j < 4; ++j) {
        const int f = tid + 256 * j;
        rS[j] = f >> 3;
        sS[j] = (((f & 7) - (f >> 3)) & 7) * 8;   // f16 elements
    }

    const _Float16* gA = Hm + (size_t)bm * INTER;
    const _Float16* gB = Wd + (size_t)bn * INTER;

    f32x4 acc[4][4] = {};

    #define STG_DN(b, k0) do { \
        _Pragma("unroll") \
        for (int j = 0; j < 4; ++j) { \
            const int f_ = tid + 256 * j; \
            const size_t off_ = (size_t)rS[j] * INTER + (size_t)(k0) + sS[j]; \
            GLDS16(gA + off_, &As[b][f_ * 8]); \
            GLDS16(gB + off_, &Bs[b][f_ * 8]); \
        } \
    } while (0)

    STG_DN(0, 0);
    __syncthreads();

    int cur = 0;
    for (int t = 0; t < NT_DN; ++t) {
        if (t + 1 < NT_DN) STG_DN(cur ^ 1, (t + 1) * BK);

        const _Float16* A_ = As[cur];
        const _Float16* B_ = Bs[cur];

        #pragma unroll
        for (int ks = 0; ks < 2; ++ks) {
            const int q = ks * 4 + lq;
            f16x8 a[4];
            #pragma unroll
            for (int im = 0; im < 4; ++im)
                a[im] = *(const f16x8*)&A_[swz8(wm + im * 16 + l15, q) * 8];
            #pragma unroll
            for (int jn = 0; jn < 4; ++jn) {
                f16x8 b = *(const f16x8*)&B_[swz8(wn + jn * 16 + l15, q) * 8];
                #pragma unroll
                for (int im = 0; im < 4; ++im)
                    acc[im][jn] = __builtin_amdgcn_mfma_f32_16x16x32_f16(a[im], b, acc[im][jn], 0, 0, 0);
            }
        }
        __syncthreads();
        cur ^= 1;
    }
    #undef STG_DN

    #pragma unroll
    for (int jn = 0; jn < 4; ++jn) {
        const int col = bn + wn + jn * 16 + l15;
        const float sd = dsc[col];
        #pragma unroll
        for (int im = 0; im < 4; ++im) {
            const int rbase = bm + wm + im * 16 + lq * 4;
            #pragma unroll
            for (int r = 0; r < 4; ++r)
                out[(size_t)(rbase + r) * HIDDEN + col] = acc[im][jn][r] * sd;
        }
    }
}

// ---------------------------------------------------------------------------
// launch
// ---------------------------------------------------------------------------
extern "C" void kernel_launch(void* const* d_in, const int* in_sizes, int n_in,
                              void* d_out, int out_size, void* d_ws, size_t ws_size,
                              hipStream_t stream) {
    const float* x   = (const float*)d_in[0];
    const float* gw  = (const float*)d_in[1];
    const float* uw  = (const float*)d_in[2];
    const float* dw  = (const float*)d_in[3];
    const float* gsc = (const float*)d_in[4];
    const float* usc = (const float*)d_in[5];
    const float* dsc = (const float*)d_in[6];
    float* out = (float*)d_out;

    // workspace layout:
    //   Xq  i8  @          0 :  8,388,608
    //   Wg8 i8  @  8,388,608 : 11,534,336
    //   Wu8 i8  @ 19,922,944 : 11,534,336
    //   Wdh f16 @ 31,457,280 : 23,068,672
    //   Hm  f16 @ 54,525,952 : 46,137,344
    //   xs  f32 @100,663,296 :     16,384
    char* ws = (char*)d_ws;
    int8_t*   Xq  = (int8_t*)(ws);
    int8_t*   Wg8 = (int8_t*)(ws + 8388608ull);
    int8_t*   Wu8 = (int8_t*)(ws + 19922944ull);
    _Float16* Wdh = (_Float16*)(ws + 31457280ull);
    _Float16* Hm  = (_Float16*)(ws + 54525952ull);
    float*    xs  = (float*)(ws + 100663296ull);

    prepass<<<TOKENS + 2048, 256, 0, stream>>>(
        x, (const float4*)gw, (const float4*)uw, (const float4*)dw,
        Xq, xs, (int*)Wg8, (int*)Wu8, (f16x4*)Wdh);

    gemm_gateup<<<(INTER / 128) * (TOKENS / 128), 256, 0, stream>>>(
        Xq, Wg8, Wu8, xs, gsc, usc, Hm);
    gemm_down<<<(HIDDEN / 128) * (TOKENS / 128), 256, 0, stream>>>(
        Hm, Wdh, dsc, out);
}

// Round 4
// 376.021 us; speedup vs baseline: 2.9968x; 1.0963x over previous
//
#include <hip/hip_runtime.h>
#include <stdint.h>
#include <stddef.h>

#define HIDDEN 2048
#define INTER  5632
#define TOKENS 4096   // B*S = 2*2048
#define BK     64     // f16 K-tile (down GEMM)  -> 128B rows, 88 iters
#define BKI    128    // i8 K-tile (gateup GEMM) -> 128B rows, 16 iters

typedef __attribute__((ext_vector_type(8))) _Float16 f16x8;
typedef __attribute__((ext_vector_type(4))) _Float16 f16x4;
typedef __attribute__((ext_vector_type(4))) float    f32x4;
typedef __attribute__((ext_vector_type(4))) int      i32x4;

// 128B-row LDS swizzle, period-8 row rotation: global segment q of row r lives
// at slot r*8 + ((q + r) & 7).  ds_read_b128 conflict unit is an 8-lane phase
// (8 x 16B = all 32 banks): for fixed q, 8 consecutive rows map to 8 DISTINCT
// bank-quads -> conflict-free (HW-verified: SQ_LDS_BANK_CONFLICT = 0, R0/R3).
__device__ __forceinline__ int swz8(int row, int q) {
    return row * 8 + ((q + row) & 7);
}

// ---------------------------------------------------------------------------
// fused prepass: blocks [0,TOKENS) quantize x per-token to i8;
// blocks [TOKENS, TOKENS+2048) grid-stride convert weights
// ---------------------------------------------------------------------------
__global__ __launch_bounds__(256)
void prepass(const float* __restrict__ x,
             const float4* __restrict__ gw, const float4* __restrict__ uw,
             const float4* __restrict__ dw,
             int8_t* __restrict__ xq, float* __restrict__ xs,
             int* __restrict__ go, int* __restrict__ uo,
             f16x4* __restrict__ dno) {
    const int tid = threadIdx.x;
    if (blockIdx.x < TOKENS) {
        const int t = blockIdx.x;
        const float4* row = (const float4*)(x + (size_t)t * HIDDEN);
        float4 v0 = row[tid * 2];
        float4 v1 = row[tid * 2 + 1];
        float m = fmaxf(fmaxf(fabsf(v0.x), fabsf(v0.y)), fmaxf(fabsf(v0.z), fabsf(v0.w)));
        m = fmaxf(m, fmaxf(fmaxf(fabsf(v1.x), fabsf(v1.y)), fmaxf(fabsf(v1.z), fabsf(v1.w))));
        #pragma unroll
        for (int off = 32; off; off >>= 1)
            m = fmaxf(m, __shfl_xor(m, off, 64));
        __shared__ float wmax[4];
        if ((tid & 63) == 0) wmax[tid >> 6] = m;
        __syncthreads();
        m = fmaxf(fmaxf(wmax[0], wmax[1]), fmaxf(wmax[2], wmax[3]));
        m = fmaxf(m, 1e-20f);
        if (tid == 0) xs[t] = m * (1.0f / 127.0f);
        const float inv = 127.0f / m;
        float vals[8] = {v0.x, v0.y, v0.z, v0.w, v1.x, v1.y, v1.z, v1.w};
        int b[8];
        #pragma unroll
        for (int i = 0; i < 8; ++i) b[i] = (int)rintf(vals[i] * inv);
        int lo = (b[0] & 255) | ((b[1] & 255) << 8) | ((b[2] & 255) << 16) | (b[3] << 24);
        int hi = (b[4] & 255) | ((b[5] & 255) << 8) | ((b[6] & 255) << 16) | (b[7] << 24);
        ((int2*)(xq + (size_t)t * HIDDEN))[tid] = make_int2(lo, hi);
        return;
    }
    const int NW4 = INTER * HIDDEN / 4;
    int i = (blockIdx.x - TOKENS) * blockDim.x + tid;
    const int stride = 2048 * blockDim.x;
    for (; i < 3 * NW4; i += stride) {
        if (i < 2 * NW4) {
            const bool is_g = i < NW4;
            const int j = is_g ? i : i - NW4;
            float4 f = is_g ? gw[j] : uw[j];
            int p = ((int)(signed char)(int)f.x & 255)
                  | (((int)(signed char)(int)f.y & 255) << 8)
                  | (((int)(signed char)(int)f.z & 255) << 16)
                  | (((int)(signed char)(int)f.w) << 24);
            if (is_g) go[j] = p; else uo[j] = p;
        } else {
            const int j = i - 2 * NW4;
            float4 f = dw[j];
            f16x4 o;
            o.x = (_Float16)f.x; o.y = (_Float16)f.y;
            o.z = (_Float16)f.z; o.w = (_Float16)f.w;
            dno[j] = o;
        }
    }
}

// ---------------------------------------------------------------------------
// GEMM1 fused (i8): H = silu(G*xs*gs) * (U*xs*us)  (fp16 out)
// 128x128 tile, BKI=128 (16 K-iters), LDS 48KB, band-swizzled grid.
// R0 structure verbatim (105us proven; R1/R3 pipeline attempts both regressed
// -- compiler's 2-barrier schedule + anti-phase block overlap is the local
// optimum).  NEW vs R0: bijective XCD-chunked pid swizzle (T1, m204):
// nwg=1408 = 8*176, p2 = (pid%8)*176 + pid/8 -> each XCD gets 176 consecutive
// band-order blocks; concurrent working set ~7MB (X-half 4MB + ~6 weight
// panels) instead of ~30MB -> L2-fill (FETCH_SIZE, 189MB = mostly Xq re-reads
// across 44 n-bands) should drop.
// ---------------------------------------------------------------------------
__global__ __launch_bounds__(256, 2)
void gemm_gateup(const int8_t* __restrict__ Xq,
                 const int8_t* __restrict__ Wg,
                 const int8_t* __restrict__ Wu,
                 const float* __restrict__ xs,
                 const float* __restrict__ gs,
                 const float* __restrict__ us,
                 _Float16* __restrict__ Hm) {
    __shared__ int8_t As [128 * BKI];
    __shared__ int8_t Bgs[128 * BKI];
    __shared__ int8_t Bus[128 * BKI];

    // XCD-chunked bijective swizzle (nwg = 1408, 1408 % 8 == 0 -> simple form)
    const int pid   = (blockIdx.x % 8) * 176 + blockIdx.x / 8;
    const int local = pid % (16 * 44);
    const int bm    = ((pid / (16 * 44)) * 16 + (local & 15)) * 128;
    const int bn    = (local >> 4) * 128;

    const int tid  = threadIdx.x;
    const int lane = tid & 63;
    const int wave = tid >> 6;
    const int wm   = (wave >> 1) * 64;
    const int wn   = (wave & 1) * 64;
    const int l15  = lane & 15;
    const int lq   = lane >> 4;

    // staging: 1024 16B-slots/tile, 256 threads x 4. slot f -> row f>>3,
    // fetches permuted global segment ((f&7) - row) & 7.
    int rowA[4], sgA[4];
    #pragma unroll
    for (int j = 0; j < 4; ++j) {
        const int f = tid + 256 * j;
        rowA[j] = f >> 3;
        sgA[j]  = (((f & 7) - rowA[j]) & 7) * 16;
    }

    i32x4 accg[4][4] = {};
    i32x4 accu[4][4] = {};

    for (int k0 = 0; k0 < HIDDEN; k0 += BKI) {
        #pragma unroll
        for (int j = 0; j < 4; ++j) {
            const int f = tid + 256 * j;
            const int8_t* pX = Xq + (size_t)(bm + rowA[j]) * HIDDEN + k0 + sgA[j];
            const int8_t* pG = Wg + (size_t)(bn + rowA[j]) * HIDDEN + k0 + sgA[j];
            const int8_t* pU = Wu + (size_t)(bn + rowA[j]) * HIDDEN + k0 + sgA[j];
            __builtin_amdgcn_global_load_lds(
                (__attribute__((address_space(1))) void*)pX,
                (__attribute__((address_space(3))) void*)&As[f * 16], 16, 0, 0);
            __builtin_amdgcn_global_load_lds(
                (__attribute__((address_space(1))) void*)pG,
                (__attribute__((address_space(3))) void*)&Bgs[f * 16], 16, 0, 0);
            __builtin_amdgcn_global_load_lds(
                (__attribute__((address_space(1))) void*)pU,
                (__attribute__((address_space(3))) void*)&Bus[f * 16], 16, 0, 0);
        }
        __syncthreads();

        #pragma unroll
        for (int ks = 0; ks < 2; ++ks) {
            const int q = ks * 4 + lq;     // segment for this MFMA k-step
            i32x4 a[4];
            #pragma unroll
            for (int im = 0; im < 4; ++im)
                a[im] = *(const i32x4*)&As[swz8(wm + im * 16 + l15, q) * 16];
            #pragma unroll
            for (int jn = 0; jn < 4; ++jn) {
                i32x4 bg = *(const i32x4*)&Bgs[swz8(wn + jn * 16 + l15, q) * 16];
                i32x4 bu = *(const i32x4*)&Bus[swz8(wn + jn * 16 + l15, q) * 16];
                #pragma unroll
                for (int im = 0; im < 4; ++im) {
                    accg[im][jn] = __builtin_amdgcn_mfma_i32_16x16x64_i8(a[im], bg, accg[im][jn], 0, 0, 0);
                    accu[im][jn] = __builtin_amdgcn_mfma_i32_16x16x64_i8(a[im], bu, accu[im][jn], 0, 0, 0);
                }
            }
        }
        __syncthreads();
    }

    #pragma unroll
    for (int jn = 0; jn < 4; ++jn) {
        const int col = bn + wn + jn * 16 + l15;
        const float sg = gs[col];
        const float su = us[col];
        #pragma unroll
        for (int im = 0; im < 4; ++im) {
            const int rbase = bm + wm + im * 16 + lq * 4;
            #pragma unroll
            for (int r = 0; r < 4; ++r) {
                const int row = rbase + r;
                const float st = xs[row];
                float g = (float)accg[im][jn][r] * st * sg;
                float u = (float)accu[im][jn][r] * st * su;
                float h = (g / (1.0f + __expf(-g))) * u;
                Hm[(size_t)row * INTER + col] = (_Float16)h;
            }
        }
    }
}

// ---------------------------------------------------------------------------
// GEMM2 (fp16): out = (H @ Wd^T) * down_s  (fp32 out)
// 128x128 tile, BK=64 (88 K-iters), LDS 32KB, band-swizzled grid.
// R0 structure verbatim.  NEW vs R0: bijective XCD-chunked pid swizzle
// (nwg = 512 = 8*64): Hm m-band + Wd panel reuse localized per XCD L2.
// ---------------------------------------------------------------------------
__global__ __launch_bounds__(256, 2)
void gemm_down(const _Float16* __restrict__ Hm,
               const _Float16* __restrict__ Wd,
               const float* __restrict__ dsc,
               float* __restrict__ out) {
    __shared__ _Float16 As[128 * BK];
    __shared__ _Float16 Bs[128 * BK];

    // XCD-chunked bijective swizzle (nwg = 512, 512 % 8 == 0 -> simple form)
    const int pid = (blockIdx.x % 8) * 64 + blockIdx.x / 8;
    const int loc = pid & 255;
    const int bm  = ((pid >> 8) * 16 + (loc & 15)) * 128;
    const int bn  = (loc >> 4) * 128;

    const int tid  = threadIdx.x;
    const int lane = tid & 63;
    const int wave = tid >> 6;
    const int wm   = (wave >> 1) * 64;
    const int wn   = (wave & 1) * 64;
    const int l15  = lane & 15;
    const int lq   = lane >> 4;

    int rowA[4], sgA[4];
    #pragma unroll
    for (int j = 0; j < 4; ++j) {
        const int f = tid + 256 * j;
        rowA[j] = f >> 3;
        sgA[j]  = (((f & 7) - rowA[j]) & 7) * 8;   // f16 elements
    }

    f32x4 acc[4][4] = {};

    for (int k0 = 0; k0 < INTER; k0 += BK) {
        #pragma unroll
        for (int j = 0; j < 4; ++j) {
            const int f = tid + 256 * j;
            const _Float16* pA = Hm + (size_t)(bm + rowA[j]) * INTER + k0 + sgA[j];
            const _Float16* pB = Wd + (size_t)(bn + rowA[j]) * INTER + k0 + sgA[j];
            __builtin_amdgcn_global_load_lds(
                (__attribute__((address_space(1))) void*)pA,
                (__attribute__((address_space(3))) void*)&As[f * 8], 16, 0, 0);
            __builtin_amdgcn_global_load_lds(
                (__attribute__((address_space(1))) void*)pB,
                (__attribute__((address_space(3))) void*)&Bs[f * 8], 16, 0, 0);
        }
        __syncthreads();

        #pragma unroll
        for (int ks = 0; ks < 2; ++ks) {
            const int q = ks * 4 + lq;
            f16x8 a[4];
            #pragma unroll
            for (int im = 0; im < 4; ++im)
                a[im] = *(const f16x8*)&As[swz8(wm + im * 16 + l15, q) * 8];
            #pragma unroll
            for (int jn = 0; jn < 4; ++jn) {
                f16x8 b = *(const f16x8*)&Bs[swz8(wn + jn * 16 + l15, q) * 8];
                #pragma unroll
                for (int im = 0; im < 4; ++im)
                    acc[im][jn] = __builtin_amdgcn_mfma_f32_16x16x32_f16(a[im], b, acc[im][jn], 0, 0, 0);
            }
        }
        __syncthreads();
    }

    #pragma unroll
    for (int jn = 0; jn < 4; ++jn) {
        const int col = bn + wn + jn * 16 + l15;
        const float sd = dsc[col];
        #pragma unroll
        for (int im = 0; im < 4; ++im) {
            const int rbase = bm + wm + im * 16 + lq * 4;
            #pragma unroll
            for (int r = 0; r < 4; ++r)
                out[(size_t)(rbase + r) * HIDDEN + col] = acc[im][jn][r] * sd;
        }
    }
}

// ---------------------------------------------------------------------------
// launch
// ---------------------------------------------------------------------------
extern "C" void kernel_launch(void* const* d_in, const int* in_sizes, int n_in,
                              void* d_out, int out_size, void* d_ws, size_t ws_size,
                              hipStream_t stream) {
    const float* x   = (const float*)d_in[0];
    const float* gw  = (const float*)d_in[1];
    const float* uw  = (const float*)d_in[2];
    const float* dw  = (const float*)d_in[3];
    const float* gsc = (const float*)d_in[4];
    const float* usc = (const float*)d_in[5];
    const float* dsc = (const float*)d_in[6];
    float* out = (float*)d_out;

    // workspace layout:
    //   Xq  i8  @          0 :  8,388,608
    //   Wg8 i8  @  8,388,608 : 11,534,336
    //   Wu8 i8  @ 19,922,944 : 11,534,336
    //   Wdh f16 @ 31,457,280 : 23,068,672
    //   Hm  f16 @ 54,525,952 : 46,137,344
    //   xs  f32 @100,663,296 :     16,384
    char* ws = (char*)d_ws;
    int8_t*   Xq  = (int8_t*)(ws);
    int8_t*   Wg8 = (int8_t*)(ws + 8388608ull);
    int8_t*   Wu8 = (int8_t*)(ws + 19922944ull);
    _Float16* Wdh = (_Float16*)(ws + 31457280ull);
    _Float16* Hm  = (_Float16*)(ws + 54525952ull);
    float*    xs  = (float*)(ws + 100663296ull);

    prepass<<<TOKENS + 2048, 256, 0, stream>>>(
        x, (const float4*)gw, (const float4*)uw, (const float4*)dw,
        Xq, xs, (int*)Wg8, (int*)Wu8, (f16x4*)Wdh);

    gemm_gateup<<<(INTER / 128) * (TOKENS / 128), 256, 0, stream>>>(
        Xq, Wg8, Wu8, xs, gsc, usc, Hm);
    gemm_down<<<(HIDDEN / 128) * (TOKENS / 128), 256, 0, stream>>>(
        Hm, Wdh, dsc, out);
}